// Round 5
// baseline (218.211 us; speedup 1.0000x reference)
//
#include <hip/hip_runtime.h>

constexpr int SRC_SIZE  = 200000;
constexpr int DST_SIZE  = 50000;
constexpr int NUM_EDGES = 800000;
constexpr int FEAT      = 32;
constexpr int BATCH     = 4;

constexpr int SCAN_BLK  = 256;
constexpr int NBLK      = (DST_SIZE + SCAN_BLK - 1) / SCAN_BLK;  // 196

// ---------- Pass 1: per-dst edge counts ----------
__global__ void count_kernel(const int* __restrict__ dst,
                             int* __restrict__ counts) {
    int e = blockIdx.x * blockDim.x + threadIdx.x;
    if (e < NUM_EDGES) atomicAdd(&counts[dst[e]], 1);
}

// ---------- Pass 2a: per-block sums of counts ----------
__global__ void scan_partials_kernel(const int* __restrict__ counts,
                                     int* __restrict__ partials) {
    __shared__ int tmp[SCAN_BLK];
    int i = blockIdx.x * SCAN_BLK + threadIdx.x;
    tmp[threadIdx.x] = (i < DST_SIZE) ? counts[i] : 0;
    __syncthreads();
    for (int off = SCAN_BLK / 2; off > 0; off >>= 1) {
        if (threadIdx.x < off) tmp[threadIdx.x] += tmp[threadIdx.x + off];
        __syncthreads();
    }
    if (threadIdx.x == 0) partials[blockIdx.x] = tmp[0];
}

// ---------- Pass 2b: block-local scan + (inline root scan) -> offsets ----------
__global__ void scan_final_kernel(const int* __restrict__ counts,
                                  const int* __restrict__ partials,
                                  int* __restrict__ offsets) {
    __shared__ int proot[SCAN_BLK];
    __shared__ int tmp[SCAN_BLK];
    const int t = threadIdx.x;

    // Every block redundantly scans the 196 partials (cheap, broadcast L2 hits).
    proot[t] = (t < NBLK) ? partials[t] : 0;
    __syncthreads();
    for (int off = 1; off < SCAN_BLK; off <<= 1) {
        int u = (t >= off) ? proot[t - off] : 0;
        __syncthreads();
        proot[t] += u;
        __syncthreads();
    }
    const int block_prefix = (blockIdx.x == 0) ? 0 : proot[blockIdx.x - 1];

    int i = blockIdx.x * SCAN_BLK + t;
    int v = (i < DST_SIZE) ? counts[i] : 0;
    tmp[t] = v;
    __syncthreads();
    for (int off = 1; off < SCAN_BLK; off <<= 1) {
        int u = (t >= off) ? tmp[t - off] : 0;
        __syncthreads();
        tmp[t] += u;
        __syncthreads();
    }
    if (i < DST_SIZE) {
        int excl = block_prefix + tmp[t] - v;
        offsets[i] = excl;
        if (i == DST_SIZE - 1) offsets[DST_SIZE] = excl + v;  // total
    }
}

// ---------- Pass 3: bucket-scatter edges into CSR order ----------
// Reuses counts as the cursor via atomicSub (counts dead after scan).
__global__ void bin_kernel(const int* __restrict__ src,
                           const int* __restrict__ dst,
                           const float* __restrict__ wts,
                           const int* __restrict__ offsets,
                           int* __restrict__ counts,
                           int2* __restrict__ epack) {
    int e = blockIdx.x * blockDim.x + threadIdx.x;
    if (e < NUM_EDGES) {
        int d = dst[e];
        int pos = atomicSub(&counts[d], 1) - 1;   // [0, count)
        int idx = offsets[d] + pos;
        epack[idx] = make_int2(src[e], __float_as_int(wts[e]));
    }
}

// ---------- Pass 4: gather ----------
// Wave = 1 dst row. Lane = (edge_group g = lane>>3, f4_slot = lane&7).
// 8 edges in flight per iteration; batch loop inside (4 independent 128B-line
// loads per edge) -> up to 32 outstanding x-loads per wave.
__global__ void gather_kernel(const float* __restrict__ x,
                              const int* __restrict__ offsets,
                              const int2* __restrict__ epack,
                              float* __restrict__ out) {
    const int wave_in_block = threadIdx.x >> 6;
    const int row = blockIdx.x * (blockDim.x >> 6) + wave_in_block;
    if (row >= DST_SIZE) return;
    const int lane = threadIdx.x & 63;
    const int g    = lane >> 3;        // edge group 0..7
    const int f4   = (lane & 7) * 4;   // feature offset

    const int start = offsets[row];
    const int n     = offsets[row + 1] - start;

    float4 acc[BATCH];
#pragma unroll
    for (int b = 0; b < BATCH; ++b) acc[b] = make_float4(0.f, 0.f, 0.f, 0.f);
    float wsum = 0.f;

    for (int i = g; i < n; i += 8) {
        const int2 p = epack[start + i];
        const float w = __int_as_float(p.y);
        wsum += w;
        const float* xs = x + (size_t)p.x * FEAT + f4;
#pragma unroll
        for (int b = 0; b < BATCH; ++b) {
            const float4 xv = *reinterpret_cast<const float4*>(
                xs + (size_t)b * SRC_SIZE * FEAT);
            acc[b].x += w * xv.x;
            acc[b].y += w * xv.y;
            acc[b].z += w * xv.z;
            acc[b].w += w * xv.w;
        }
    }

    // Reduce across the 8 edge groups (lane bits 3,4,5).
#pragma unroll
    for (int m = 8; m <= 32; m <<= 1) {
#pragma unroll
        for (int b = 0; b < BATCH; ++b) {
            acc[b].x += __shfl_xor(acc[b].x, m);
            acc[b].y += __shfl_xor(acc[b].y, m);
            acc[b].z += __shfl_xor(acc[b].z, m);
            acc[b].w += __shfl_xor(acc[b].w, m);
        }
        wsum += __shfl_xor(wsum, m);
    }

    const float scale = 1.f / (wsum + 1e-8f);
    // Lanes 0..31 write: b = lane>>3, f4 slot = lane&7  (512B contiguous/row).
    if (lane < 32) {
        const int wb = lane >> 3;
        float4 o = acc[wb];
        o.x *= scale; o.y *= scale; o.z *= scale; o.w *= scale;
        *reinterpret_cast<float4*>(
            out + ((size_t)wb * DST_SIZE + row) * FEAT + f4) = o;
    }
}

// ---------- Fallback (atomic path, used only if ws too small) ----------
__global__ void norm_kernel_fb(const int* __restrict__ dst,
                               const float* __restrict__ wts,
                               float* __restrict__ norm) {
    int e = blockIdx.x * blockDim.x + threadIdx.x;
    if (e < NUM_EDGES) atomicAdd(&norm[dst[e]], wts[e]);
}

__global__ void scatter_kernel_fb(const float* __restrict__ x,
                                  const int* __restrict__ src,
                                  const int* __restrict__ dst,
                                  const float* __restrict__ wts,
                                  const float* __restrict__ norm,
                                  float* __restrict__ out) {
    long long tid = (long long)blockIdx.x * blockDim.x + threadIdx.x;
    if (tid >= (long long)NUM_EDGES * 8) return;
    int e = (int)(tid >> 3);
    int g = ((int)tid & 7) * 4;
    int s = src[e];
    int d = dst[e];
    float w = wts[e] / (norm[d] + 1e-8f);
#pragma unroll
    for (int b = 0; b < BATCH; ++b) {
        const float4 xv = *reinterpret_cast<const float4*>(
            x + ((size_t)b * SRC_SIZE + s) * FEAT + g);
        float* o = out + ((size_t)b * DST_SIZE + d) * FEAT + g;
        atomicAdd(o + 0, w * xv.x);
        atomicAdd(o + 1, w * xv.y);
        atomicAdd(o + 2, w * xv.z);
        atomicAdd(o + 3, w * xv.w);
    }
}

extern "C" void kernel_launch(void* const* d_in, const int* in_sizes, int n_in,
                              void* d_out, int out_size, void* d_ws, size_t ws_size,
                              hipStream_t stream) {
    const float* x   = (const float*)d_in[0];
    const int*   ei  = (const int*)d_in[1];   // (2, E): src row then dst row
    const float* wts = (const float*)d_in[2];
    const int* src = ei;
    const int* dst = ei + NUM_EDGES;
    float* out = (float*)d_out;

    // Workspace layout. epack first (8-byte aligned), then 4-byte arrays.
    char* ws = (char*)d_ws;
    int2*  epack   = (int2*)(ws);                                        // NUM_EDGES
    int*   counts  = (int*)(ws + (size_t)NUM_EDGES * 8);                 // DST_SIZE
    int*   offsets = (int*)(ws + (size_t)NUM_EDGES * 8 + (size_t)DST_SIZE * 4);  // DST_SIZE+1
    int*   partials= (int*)(ws + (size_t)NUM_EDGES * 8 + (2 * (size_t)DST_SIZE + 1) * 4); // NBLK
    size_t needed  = (size_t)NUM_EDGES * 8 + (2 * (size_t)DST_SIZE + 1 + NBLK) * 4;

    int threads = 256;
    int eblocks = (NUM_EDGES + threads - 1) / threads;

    if (ws_size < needed) {
        float* norm = (float*)d_ws;
        hipMemsetAsync(norm, 0, (size_t)DST_SIZE * sizeof(float), stream);
        hipMemsetAsync(out, 0, (size_t)out_size * sizeof(float), stream);
        norm_kernel_fb<<<eblocks, threads, 0, stream>>>(dst, wts, norm);
        long long total = (long long)NUM_EDGES * 8;
        scatter_kernel_fb<<<(int)((total + threads - 1) / threads), threads, 0, stream>>>(
            x, src, dst, wts, norm, out);
        return;
    }

    hipMemsetAsync(counts, 0, (size_t)DST_SIZE * sizeof(int), stream);

    count_kernel<<<eblocks, threads, 0, stream>>>(dst, counts);
    scan_partials_kernel<<<NBLK, SCAN_BLK, 0, stream>>>(counts, partials);
    scan_final_kernel<<<NBLK, SCAN_BLK, 0, stream>>>(counts, partials, offsets);
    bin_kernel<<<eblocks, threads, 0, stream>>>(src, dst, wts, offsets, counts, epack);

    // 4 waves (4 rows) per block.
    int gblocks = (DST_SIZE + 3) / 4;
    gather_kernel<<<gblocks, 256, 0, stream>>>(x, offsets, epack, out);
}

// Round 6
// 148.076 us; speedup vs baseline: 1.4736x; 1.4736x over previous
//
#include <hip/hip_runtime.h>

constexpr int SRC_SIZE  = 200000;
constexpr int DST_SIZE  = 50000;
constexpr int NUM_EDGES = 800000;
constexpr int FEAT      = 32;
constexpr int BATCH     = 4;

constexpr int SCAN_BLK  = 256;
constexpr int NBLK      = (DST_SIZE + SCAN_BLK - 1) / SCAN_BLK;  // 196

// ---------- Pass 1: per-dst edge counts ----------
__global__ void count_kernel(const int* __restrict__ dst,
                             int* __restrict__ counts) {
    int e = blockIdx.x * blockDim.x + threadIdx.x;
    if (e < NUM_EDGES) atomicAdd(&counts[dst[e]], 1);
}

// ---------- Pass 2a: per-block sums of counts ----------
__global__ void scan_partials_kernel(const int* __restrict__ counts,
                                     int* __restrict__ partials) {
    __shared__ int tmp[SCAN_BLK];
    int i = blockIdx.x * SCAN_BLK + threadIdx.x;
    tmp[threadIdx.x] = (i < DST_SIZE) ? counts[i] : 0;
    __syncthreads();
    for (int off = SCAN_BLK / 2; off > 0; off >>= 1) {
        if (threadIdx.x < off) tmp[threadIdx.x] += tmp[threadIdx.x + off];
        __syncthreads();
    }
    if (threadIdx.x == 0) partials[blockIdx.x] = tmp[0];
}

// ---------- Pass 2b: block-local scan + (inline root scan) -> offsets ----------
__global__ void scan_final_kernel(const int* __restrict__ counts,
                                  const int* __restrict__ partials,
                                  int* __restrict__ offsets) {
    __shared__ int proot[SCAN_BLK];
    __shared__ int tmp[SCAN_BLK];
    const int t = threadIdx.x;

    proot[t] = (t < NBLK) ? partials[t] : 0;
    __syncthreads();
    for (int off = 1; off < SCAN_BLK; off <<= 1) {
        int u = (t >= off) ? proot[t - off] : 0;
        __syncthreads();
        proot[t] += u;
        __syncthreads();
    }
    const int block_prefix = (blockIdx.x == 0) ? 0 : proot[blockIdx.x - 1];

    int i = blockIdx.x * SCAN_BLK + t;
    int v = (i < DST_SIZE) ? counts[i] : 0;
    tmp[t] = v;
    __syncthreads();
    for (int off = 1; off < SCAN_BLK; off <<= 1) {
        int u = (t >= off) ? tmp[t - off] : 0;
        __syncthreads();
        tmp[t] += u;
        __syncthreads();
    }
    if (i < DST_SIZE) {
        int excl = block_prefix + tmp[t] - v;
        offsets[i] = excl;
        if (i == DST_SIZE - 1) offsets[DST_SIZE] = excl + v;  // total
    }
}

// ---------- Pass 3: bucket-scatter edges into CSR order ----------
__global__ void bin_kernel(const int* __restrict__ src,
                           const int* __restrict__ dst,
                           const float* __restrict__ wts,
                           const int* __restrict__ offsets,
                           int* __restrict__ counts,
                           int2* __restrict__ epack) {
    int e = blockIdx.x * blockDim.x + threadIdx.x;
    if (e < NUM_EDGES) {
        int d = dst[e];
        int pos = atomicSub(&counts[d], 1) - 1;   // [0, count)
        int idx = offsets[d] + pos;
        epack[idx] = make_int2(src[e], __float_as_int(wts[e]));
    }
}

// ---------- Pass 4: gather ----------
// Wave = 1 dst row. Lane = (edge_group g = lane>>3, f4_slot = lane&7).
// 8 edges in flight per iteration; batch loop inside (4 independent 128B-line
// loads per edge) -> up to 32 outstanding x-loads per wave.
// ALL acc indices are compile-time constants (rule #20: no runtime-indexed
// register arrays — the round-5 version paid 64KB LDS scratch for one).
__global__ void gather_kernel(const float* __restrict__ x,
                              const int* __restrict__ offsets,
                              const int2* __restrict__ epack,
                              float* __restrict__ out) {
    const int wave_in_block = threadIdx.x >> 6;
    const int row = blockIdx.x * (blockDim.x >> 6) + wave_in_block;
    if (row >= DST_SIZE) return;
    const int lane = threadIdx.x & 63;
    const int g    = lane >> 3;        // edge group 0..7
    const int f4   = (lane & 7) * 4;   // feature offset

    const int start = offsets[row];
    const int n     = offsets[row + 1] - start;

    float4 acc0 = make_float4(0.f, 0.f, 0.f, 0.f);
    float4 acc1 = acc0, acc2 = acc0, acc3 = acc0;
    float wsum = 0.f;

    for (int i = g; i < n; i += 8) {
        const int2 p = epack[start + i];
        const float w = __int_as_float(p.y);
        wsum += w;
        const float* xs = x + (size_t)p.x * FEAT + f4;
        const float4 v0 = *reinterpret_cast<const float4*>(xs);
        const float4 v1 = *reinterpret_cast<const float4*>(xs + (size_t)1 * SRC_SIZE * FEAT);
        const float4 v2 = *reinterpret_cast<const float4*>(xs + (size_t)2 * SRC_SIZE * FEAT);
        const float4 v3 = *reinterpret_cast<const float4*>(xs + (size_t)3 * SRC_SIZE * FEAT);
        acc0.x += w * v0.x; acc0.y += w * v0.y; acc0.z += w * v0.z; acc0.w += w * v0.w;
        acc1.x += w * v1.x; acc1.y += w * v1.y; acc1.z += w * v1.z; acc1.w += w * v1.w;
        acc2.x += w * v2.x; acc2.y += w * v2.y; acc2.z += w * v2.z; acc2.w += w * v2.w;
        acc3.x += w * v3.x; acc3.y += w * v3.y; acc3.z += w * v3.z; acc3.w += w * v3.w;
    }

    // Reduce across the 8 edge groups (lane bits 3,4,5). Static unroll.
#pragma unroll
    for (int m = 8; m <= 32; m <<= 1) {
        acc0.x += __shfl_xor(acc0.x, m); acc0.y += __shfl_xor(acc0.y, m);
        acc0.z += __shfl_xor(acc0.z, m); acc0.w += __shfl_xor(acc0.w, m);
        acc1.x += __shfl_xor(acc1.x, m); acc1.y += __shfl_xor(acc1.y, m);
        acc1.z += __shfl_xor(acc1.z, m); acc1.w += __shfl_xor(acc1.w, m);
        acc2.x += __shfl_xor(acc2.x, m); acc2.y += __shfl_xor(acc2.y, m);
        acc2.z += __shfl_xor(acc2.z, m); acc2.w += __shfl_xor(acc2.w, m);
        acc3.x += __shfl_xor(acc3.x, m); acc3.y += __shfl_xor(acc3.y, m);
        acc3.z += __shfl_xor(acc3.z, m); acc3.w += __shfl_xor(acc3.w, m);
        wsum += __shfl_xor(wsum, m);
    }

    const float scale = 1.f / (wsum + 1e-8f);
    const int wb = lane >> 3;
    // Exec-masked static stores: lanes 0..7 -> batch0, 8..15 -> batch1, etc.
    if (lane < 32) {
        float* obase = out + (size_t)wb * DST_SIZE * FEAT + (size_t)row * FEAT + f4;
        if (wb == 0) {
            float4 o = acc0; o.x *= scale; o.y *= scale; o.z *= scale; o.w *= scale;
            *reinterpret_cast<float4*>(obase) = o;
        } else if (wb == 1) {
            float4 o = acc1; o.x *= scale; o.y *= scale; o.z *= scale; o.w *= scale;
            *reinterpret_cast<float4*>(obase) = o;
        } else if (wb == 2) {
            float4 o = acc2; o.x *= scale; o.y *= scale; o.z *= scale; o.w *= scale;
            *reinterpret_cast<float4*>(obase) = o;
        } else {
            float4 o = acc3; o.x *= scale; o.y *= scale; o.z *= scale; o.w *= scale;
            *reinterpret_cast<float4*>(obase) = o;
        }
    }
}

// ---------- Fallback (atomic path, used only if ws too small) ----------
__global__ void norm_kernel_fb(const int* __restrict__ dst,
                               const float* __restrict__ wts,
                               float* __restrict__ norm) {
    int e = blockIdx.x * blockDim.x + threadIdx.x;
    if (e < NUM_EDGES) atomicAdd(&norm[dst[e]], wts[e]);
}

__global__ void scatter_kernel_fb(const float* __restrict__ x,
                                  const int* __restrict__ src,
                                  const int* __restrict__ dst,
                                  const float* __restrict__ wts,
                                  const float* __restrict__ norm,
                                  float* __restrict__ out) {
    long long tid = (long long)blockIdx.x * blockDim.x + threadIdx.x;
    if (tid >= (long long)NUM_EDGES * 8) return;
    int e = (int)(tid >> 3);
    int g = ((int)tid & 7) * 4;
    int s = src[e];
    int d = dst[e];
    float w = wts[e] / (norm[d] + 1e-8f);
#pragma unroll
    for (int b = 0; b < BATCH; ++b) {
        const float4 xv = *reinterpret_cast<const float4*>(
            x + ((size_t)b * SRC_SIZE + s) * FEAT + g);
        float* o = out + ((size_t)b * DST_SIZE + d) * FEAT + g;
        atomicAdd(o + 0, w * xv.x);
        atomicAdd(o + 1, w * xv.y);
        atomicAdd(o + 2, w * xv.z);
        atomicAdd(o + 3, w * xv.w);
    }
}

extern "C" void kernel_launch(void* const* d_in, const int* in_sizes, int n_in,
                              void* d_out, int out_size, void* d_ws, size_t ws_size,
                              hipStream_t stream) {
    const float* x   = (const float*)d_in[0];
    const int*   ei  = (const int*)d_in[1];   // (2, E): src row then dst row
    const float* wts = (const float*)d_in[2];
    const int* src = ei;
    const int* dst = ei + NUM_EDGES;
    float* out = (float*)d_out;

    // Workspace layout. epack first (8-byte aligned), then 4-byte arrays.
    char* ws = (char*)d_ws;
    int2*  epack   = (int2*)(ws);                                        // NUM_EDGES
    int*   counts  = (int*)(ws + (size_t)NUM_EDGES * 8);                 // DST_SIZE
    int*   offsets = (int*)(ws + (size_t)NUM_EDGES * 8 + (size_t)DST_SIZE * 4);  // DST_SIZE+1
    int*   partials= (int*)(ws + (size_t)NUM_EDGES * 8 + (2 * (size_t)DST_SIZE + 1) * 4); // NBLK
    size_t needed  = (size_t)NUM_EDGES * 8 + (2 * (size_t)DST_SIZE + 1 + NBLK) * 4;

    int threads = 256;
    int eblocks = (NUM_EDGES + threads - 1) / threads;

    if (ws_size < needed) {
        float* norm = (float*)d_ws;
        hipMemsetAsync(norm, 0, (size_t)DST_SIZE * sizeof(float), stream);
        hipMemsetAsync(out, 0, (size_t)out_size * sizeof(float), stream);
        norm_kernel_fb<<<eblocks, threads, 0, stream>>>(dst, wts, norm);
        long long total = (long long)NUM_EDGES * 8;
        scatter_kernel_fb<<<(int)((total + threads - 1) / threads), threads, 0, stream>>>(
            x, src, dst, wts, norm, out);
        return;
    }

    hipMemsetAsync(counts, 0, (size_t)DST_SIZE * sizeof(int), stream);

    count_kernel<<<eblocks, threads, 0, stream>>>(dst, counts);
    scan_partials_kernel<<<NBLK, SCAN_BLK, 0, stream>>>(counts, partials);
    scan_final_kernel<<<NBLK, SCAN_BLK, 0, stream>>>(counts, partials, offsets);
    bin_kernel<<<eblocks, threads, 0, stream>>>(src, dst, wts, offsets, counts, epack);

    // 4 waves (4 rows) per block.
    int gblocks = (DST_SIZE + 3) / 4;
    gather_kernel<<<gblocks, 256, 0, stream>>>(x, offsets, epack, out);
}